// Round 1
// baseline (64.618 us; speedup 1.0000x reference)
//
#include <hip/hip_runtime.h>
#include <stdint.h>

// Sizes: B=2, L=256, CB=64, D=512, H=8, HD=64.  BI = B*L = 512 rows.
// ws layout (floats):
//   MkAll [512*512] @ 0        MkAll[e*512 + h*64+c] = sum_d Wq[e][h*64+d]*Wk[c][h*64+d]
//   Mv    [512*512] @ 262144   Mv[(h*64+c)*512 + f]  = sum_d Wv[c][h*64+d]*Wo[h*64+d][f]
//   Cb    [512]     @ 524288   Cb[h*64+c] = sum_d bq[h*64+d]*Wk[c][h*64+d]
//   bvoP  [8*512]   @ 524800   bvoP[h*512+f] = sum_{d<64} bv[h*64+d]*Wo[h*64+d][f]
//   QWkP  [2*512*512] @ 528896 (split-K partials; also reused as GP by K3)
//   wp    [512*512] @ 1053184
// total 1315328 floats = 5.26 MB

__device__ __forceinline__ unsigned bf16r(float f) {
  unsigned u = __float_as_uint(f);
  return (u + 0x7fffu + ((u >> 16) & 1u)) >> 16;
}
__device__ __forceinline__ unsigned packbf(float a, float b) {
  return bf16r(a) | (bf16r(b) << 16);
}
__device__ __forceinline__ float ulo(unsigned u) { return __uint_as_float(u << 16); }
__device__ __forceinline__ float uhi(unsigned u) { return __uint_as_float(u & 0xffff0000u); }

// ---------------- K0: weight prep (Mk / Mv / Cb / bvoP) ----------------
__global__ __launch_bounds__(256) void k0_prep(
    const float* __restrict__ Wq, const float* __restrict__ bq,
    const float* __restrict__ Wk, const float* __restrict__ Wv,
    const float* __restrict__ Wo, const float* __restrict__ bv,
    float* __restrict__ MkAll, float* __restrict__ Mv,
    float* __restrict__ Cb, float* __restrict__ bvoP) {
  __shared__ float LA[64][68];   // transposed [d][row]
  __shared__ float LB[64][68];   // Mk: [d][c] (transposed Wk); Mv: [d][f] (direct Wo)
  __shared__ float bvec[64];
  const int t = threadIdx.x;
  const int bid = blockIdx.x;
  const bool isMk = bid < 64;
  const int sub = isMk ? bid : bid - 64;
  const int h = sub >> 3;
  const int tile = (sub & 7) * 64;   // e-base (Mk) or f-base (Mv)

  // LA[d][row]: Mk: Wq[tile+row][h*64+d]; Mv: Wv[row][h*64+d]
  for (int r = 0; r < 4; ++r) {
    int idx = t + 256 * r;
    int row = idx >> 4;
    int dq = idx & 15;
    const float* src = isMk ? (Wq + (size_t)(tile + row) * 512 + h * 64 + dq * 4)
                            : (Wv + (size_t)row * 512 + h * 64 + dq * 4);
    float4 v = *(const float4*)src;
    LA[dq * 4 + 0][row] = v.x; LA[dq * 4 + 1][row] = v.y;
    LA[dq * 4 + 2][row] = v.z; LA[dq * 4 + 3][row] = v.w;
  }
  // LB
  for (int r = 0; r < 4; ++r) {
    int idx = t + 256 * r;
    if (isMk) {
      int c = idx >> 4, dq = idx & 15;
      float4 v = *(const float4*)&Wk[(size_t)c * 512 + h * 64 + dq * 4];
      LB[dq * 4 + 0][c] = v.x; LB[dq * 4 + 1][c] = v.y;
      LB[dq * 4 + 2][c] = v.z; LB[dq * 4 + 3][c] = v.w;
    } else {
      int d = idx >> 4, fq = idx & 15;
      float4 v = *(const float4*)&Wo[(size_t)(h * 64 + d) * 512 + tile + fq * 4];
      *(float4*)&LB[d][fq * 4] = v;
    }
  }
  if (t < 16) {
    const float* bsrc = isMk ? bq : bv;
    float4 v = *(const float4*)&bsrc[h * 64 + t * 4];
    bvec[t * 4 + 0] = v.x; bvec[t * 4 + 1] = v.y;
    bvec[t * 4 + 2] = v.z; bvec[t * 4 + 3] = v.w;
  }
  __syncthreads();

  const int r0 = (t >> 4) * 4;
  const int c0 = (t & 15) * 4;
  float acc[4][4] = {};
  #pragma unroll 8
  for (int d = 0; d < 64; ++d) {
    float4 a = *(float4*)&LA[d][r0];
    float4 b = *(float4*)&LB[d][c0];
    acc[0][0] += a.x * b.x; acc[0][1] += a.x * b.y; acc[0][2] += a.x * b.z; acc[0][3] += a.x * b.w;
    acc[1][0] += a.y * b.x; acc[1][1] += a.y * b.y; acc[1][2] += a.y * b.z; acc[1][3] += a.y * b.w;
    acc[2][0] += a.z * b.x; acc[2][1] += a.z * b.y; acc[2][2] += a.z * b.z; acc[2][3] += a.z * b.w;
    acc[3][0] += a.w * b.x; acc[3][1] += a.w * b.y; acc[3][2] += a.w * b.z; acc[3][3] += a.w * b.w;
  }
  if (isMk) {
    #pragma unroll
    for (int i = 0; i < 4; ++i) {
      float4 o = make_float4(acc[i][0], acc[i][1], acc[i][2], acc[i][3]);
      *(float4*)&MkAll[(size_t)(tile + r0 + i) * 512 + h * 64 + c0] = o;
    }
    if ((sub & 7) == 0 && t < 64) {
      float s = 0.f;
      for (int d = 0; d < 64; ++d) s += bvec[d] * LB[d][t];
      Cb[h * 64 + t] = s;
    }
  } else {
    #pragma unroll
    for (int i = 0; i < 4; ++i) {
      float4 o = make_float4(acc[i][0], acc[i][1], acc[i][2], acc[i][3]);
      *(float4*)&Mv[(size_t)(h * 64 + r0 + i) * 512 + tile + c0] = o;
    }
    if (t < 64) {
      float s = 0.f;
      for (int d = 0; d < 64; ++d) s += bvec[d] * LB[d][t];
      bvoP[h * 512 + tile + t] = s;
    }
  }
}

// ---------------- shared 512x512x512 fp32 GEMM, split-K=2 ----------------
// grid (8 ntiles, 16 mtiles, 2 z); tile 32 rows x 64 cols; P[z*262144 + m*512 + n]
__global__ __launch_bounds__(256) void k_gemm512(
    const float* __restrict__ A, const float* __restrict__ Bm,
    const float* __restrict__ Cbias, float* __restrict__ P) {
  __shared__ float As[32][34];   // [k][m], transposed
  __shared__ float Bs[32][68];   // [k][n]
  const int t = threadIdx.x;
  const int n0 = blockIdx.x * 64;
  const int m0 = blockIdx.y * 32;
  const int kb = blockIdx.z * 256;
  const int tm = t >> 4, tn = t & 15;
  float acc[2][4] = {};
  for (int kc = 0; kc < 8; ++kc) {
    const int k0 = kb + kc * 32;
    {
      int m = t >> 3, kq = t & 7;
      float4 v = *(const float4*)&A[(size_t)(m0 + m) * 512 + k0 + kq * 4];
      As[kq * 4 + 0][m] = v.x; As[kq * 4 + 1][m] = v.y;
      As[kq * 4 + 2][m] = v.z; As[kq * 4 + 3][m] = v.w;
    }
    #pragma unroll
    for (int r = 0; r < 2; ++r) {
      int idx = t + 256 * r;
      int k = idx >> 4, nq = idx & 15;
      float4 v = *(const float4*)&Bm[(size_t)(k0 + k) * 512 + n0 + nq * 4];
      *(float4*)&Bs[k][nq * 4] = v;
    }
    __syncthreads();
    #pragma unroll
    for (int k = 0; k < 32; ++k) {
      float2 a = *(float2*)&As[k][tm * 2];
      float4 b = *(float4*)&Bs[k][tn * 4];
      acc[0][0] += a.x * b.x; acc[0][1] += a.x * b.y;
      acc[0][2] += a.x * b.z; acc[0][3] += a.x * b.w;
      acc[1][0] += a.y * b.x; acc[1][1] += a.y * b.y;
      acc[1][2] += a.y * b.z; acc[1][3] += a.y * b.w;
    }
    __syncthreads();
  }
  float4 cb = make_float4(0.f, 0.f, 0.f, 0.f);
  if (Cbias != nullptr && blockIdx.z == 0) {
    cb = *(const float4*)&Cbias[n0 + tn * 4];
  }
  #pragma unroll
  for (int r = 0; r < 2; ++r) {
    float4 o = make_float4(acc[r][0] + cb.x, acc[r][1] + cb.y,
                           acc[r][2] + cb.z, acc[r][3] + cb.w);
    *(float4*)&P[(size_t)blockIdx.z * 262144 + (size_t)(m0 + tm * 2 + r) * 512 + n0 + tn * 4] = o;
  }
}

// ---------------- K2: per-(b,i) scores -> softmax -> wp ----------------
__global__ __launch_bounds__(256) void k2_attn(
    const float* __restrict__ pair, const float* __restrict__ QWkP,
    float* __restrict__ wp) {
  __shared__ unsigned Pu[256][36];   // pair row j as bf16 pairs (64 used of 72), 144B stride
  __shared__ float qk[512];
  __shared__ float wls[8][260];
  __shared__ float redA[4][8];
  __shared__ float redB[4][8];
  __shared__ float wpP[128][4];
  const int t = threadIdx.x;
  const int bi = blockIdx.x;
  const float* pr = pair + (size_t)bi * (256 * 64);

  #pragma unroll
  for (int r = 0; r < 2; ++r) {
    int f = t + 256 * r;
    qk[f] = QWkP[(size_t)bi * 512 + f] + QWkP[262144 + (size_t)bi * 512 + f];
  }
  #pragma unroll
  for (int r = 0; r < 16; ++r) {
    int idx = t + 256 * r;
    int j = idx >> 4, cq = idx & 15;
    float4 v = *(const float4*)&pr[j * 64 + cq * 4];
    Pu[j][cq * 2] = packbf(v.x, v.y);
    Pu[j][cq * 2 + 1] = packbf(v.z, v.w);
  }
  __syncthreads();

  // scores for j = t, all 8 heads
  float pf[64];
  #pragma unroll
  for (int cq = 0; cq < 16; ++cq) {
    uint2 u = *(uint2*)&Pu[t][cq * 2];
    pf[cq * 4 + 0] = ulo(u.x); pf[cq * 4 + 1] = uhi(u.x);
    pf[cq * 4 + 2] = ulo(u.y); pf[cq * 4 + 3] = uhi(u.y);
  }
  float s[8];
  #pragma unroll
  for (int h = 0; h < 8; ++h) {
    float a = 0.f;
    #pragma unroll
    for (int c4 = 0; c4 < 16; ++c4) {
      float4 q = *(float4*)&qk[h * 64 + c4 * 4];
      a += pf[c4 * 4 + 0] * q.x + pf[c4 * 4 + 1] * q.y +
           pf[c4 * 4 + 2] * q.z + pf[c4 * 4 + 3] * q.w;
    }
    s[h] = a * 0.125f;   // 1/sqrt(64)
  }

  const int wv = t >> 6, lane = t & 63;
  #pragma unroll
  for (int h = 0; h < 8; ++h) {
    float v = s[h];
    for (int o = 32; o; o >>= 1) v = fmaxf(v, __shfl_xor(v, o, 64));
    if (lane == 0) redA[wv][h] = v;
  }
  __syncthreads();
  float mx[8];
  #pragma unroll
  for (int h = 0; h < 8; ++h)
    mx[h] = fmaxf(fmaxf(redA[0][h], redA[1][h]), fmaxf(redA[2][h], redA[3][h]));
  float e[8];
  #pragma unroll
  for (int h = 0; h < 8; ++h) {
    e[h] = __expf(s[h] - mx[h]);
    float v = e[h];
    for (int o = 32; o; o >>= 1) v += __shfl_xor(v, o, 64);
    if (lane == 0) redB[wv][h] = v;
  }
  __syncthreads();
  #pragma unroll
  for (int h = 0; h < 8; ++h) {
    float Z = redB[0][h] + redB[1][h] + redB[2][h] + redB[3][h];
    wls[h][t] = e[h] / Z;
  }
  __syncthreads();

  // wp[h][c] = sum_j w[h][j] * pair[j][c]
  const int c4 = t & 15;
  const int hh = (t >> 4) & 7;
  const int jh = t >> 7;
  float a0 = 0.f, a1 = 0.f, a2 = 0.f, a3 = 0.f;
  for (int jj = 0; jj < 128; ++jj) {
    int j = jh * 128 + jj;
    float w = wls[hh][j];
    uint2 u = *(uint2*)&Pu[j][c4 * 2];
    a0 += w * ulo(u.x); a1 += w * uhi(u.x);
    a2 += w * ulo(u.y); a3 += w * uhi(u.y);
  }
  if (jh == 1) {
    wpP[t - 128][0] = a0; wpP[t - 128][1] = a1;
    wpP[t - 128][2] = a2; wpP[t - 128][3] = a3;
  }
  __syncthreads();
  if (jh == 0) {
    a0 += wpP[t][0]; a1 += wpP[t][1]; a2 += wpP[t][2]; a3 += wpP[t][3];
    float4 o = make_float4(a0, a1, a2, a3);
    *(float4*)&wp[(size_t)bi * 512 + hh * 64 + c4 * 4] = o;
  }
}

// ---------------- K4: residual + biases + LayerNorm ----------------
__global__ __launch_bounds__(256) void k4_ln(
    const float* __restrict__ GP, const float* __restrict__ bvoP,
    const float* __restrict__ bo, const float* __restrict__ x,
    const float* __restrict__ gamma, const float* __restrict__ beta,
    float* __restrict__ out) {
  __shared__ float red[2][4];
  const int t = threadIdx.x, bi = blockIdx.x;
  float y[2];
  #pragma unroll
  for (int r = 0; r < 2; ++r) {
    int f = t + 256 * r;
    float v = GP[(size_t)bi * 512 + f] + GP[262144 + (size_t)bi * 512 + f] +
              bo[f] + x[(size_t)bi * 512 + f];
    #pragma unroll
    for (int h = 0; h < 8; ++h) v += bvoP[h * 512 + f];
    y[r] = v;
  }
  float s = y[0] + y[1];
  float q = y[0] * y[0] + y[1] * y[1];
  for (int o = 32; o; o >>= 1) { s += __shfl_xor(s, o, 64); q += __shfl_xor(q, o, 64); }
  const int wv = t >> 6, lane = t & 63;
  if (lane == 0) { red[0][wv] = s; red[1][wv] = q; }
  __syncthreads();
  float S = red[0][0] + red[0][1] + red[0][2] + red[0][3];
  float Qs = red[1][0] + red[1][1] + red[1][2] + red[1][3];
  float mu = S * (1.f / 512.f);
  float var = Qs * (1.f / 512.f) - mu * mu;
  float rstd = rsqrtf(var + 1e-5f);
  #pragma unroll
  for (int r = 0; r < 2; ++r) {
    int f = t + 256 * r;
    out[(size_t)bi * 512 + f] = (y[r] - mu) * rstd * gamma[f] + beta[f];
  }
}

extern "C" void kernel_launch(void* const* d_in, const int* in_sizes, int n_in,
                              void* d_out, int out_size, void* d_ws, size_t ws_size,
                              hipStream_t stream) {
  (void)in_sizes; (void)n_in; (void)out_size; (void)ws_size;
  const float* x     = (const float*)d_in[0];
  const float* pair  = (const float*)d_in[1];
  const float* Wq    = (const float*)d_in[2];
  const float* bq    = (const float*)d_in[3];
  const float* Wk    = (const float*)d_in[4];
  // d_in[5] = bk: Q·bk is constant over j -> cancels in softmax
  const float* Wv    = (const float*)d_in[6];
  const float* bv    = (const float*)d_in[7];
  const float* Wo    = (const float*)d_in[8];
  const float* bo    = (const float*)d_in[9];
  const float* gamma = (const float*)d_in[10];
  const float* beta  = (const float*)d_in[11];

  float* ws    = (float*)d_ws;
  float* MkAll = ws;
  float* Mv    = ws + 262144;
  float* Cb    = ws + 524288;
  float* bvoP  = ws + 524800;
  float* QWkP  = ws + 528896;
  float* wp    = ws + 1053184;
  float* GP    = QWkP;   // QWkP dead after K2; reuse for out-GEMM partials

  k0_prep<<<128, 256, 0, stream>>>(Wq, bq, Wk, Wv, Wo, bv, MkAll, Mv, Cb, bvoP);
  k_gemm512<<<dim3(8, 16, 2), 256, 0, stream>>>(x, MkAll, Cb, QWkP);
  k2_attn<<<512, 256, 0, stream>>>(pair, QWkP, wp);
  k_gemm512<<<dim3(8, 16, 2), 256, 0, stream>>>(wp, Mv, nullptr, GP);
  k4_ln<<<512, 256, 0, stream>>>(GP, bvoP, bo, x, gamma, beta, (float*)d_out);
}

// Round 2
// 31.527 us; speedup vs baseline: 2.0496x; 2.0496x over previous
//
#include <hip/hip_runtime.h>
#include <hip/hip_bf16.h>
#include <stdint.h>

// B=2, L=256, CB=64, D=512, H=8, HD=64. BI = B*L = 512.
// Pipeline (all MFMA bf16, fp32 accum):
//   K0: MkT[hc][e] = (Wq Wk^T per head)^T, MvT[f][hc] = (Wv@Wo per head)^T, Cb, bvoP, xb=bf16(x)
//   G1: QWkP[z] = xb @ Mk  (4-way split-K partials, fp32)
//   K2: per (b,i): scores MFMA -> softmax -> wp MFMA -> wp (bf16)
//   G2: GP[z] = wp @ Mv
//   K4: LayerNorm(sum(GP) + bvoSum + bo + x)
//
// ws layout (float offsets):
//   MkT  @ 0       (131072 u32 = 512x512 bf16, row hc, k=e contiguous)
//   MvT  @ 131072  (row f, k=hc contiguous)
//   xb   @ 262144  (512x512 bf16 row-major)
//   wp   @ 393216  (512x512 bf16 row-major)
//   Cb   @ 524288  (512 f32)
//   bvoP @ 524800  (8*512 f32)
//   QWkP @ 528896  (4*262144 f32; reused as GP by G2)

using u32  = unsigned int;
using s8bf = __attribute__((ext_vector_type(8))) short;   // 8 bf16 = 4 VGPR
using f32x4 = __attribute__((ext_vector_type(4))) float;

union U4 { uint4 u; s8bf v; };

__device__ __forceinline__ u32 pack2(float a, float b) {
  __hip_bfloat162 h2 = __float22bfloat162_rn(make_float2(a, b));
  union { __hip_bfloat162 h; u32 u; } cv; cv.h = h2; return cv.u;
}

// ---------------- K0: weight prep + x->bf16 ----------------
__global__ __launch_bounds__(256) void k0_prep(
    const float* __restrict__ Wq, const float* __restrict__ bq,
    const float* __restrict__ Wk, const float* __restrict__ Wv,
    const float* __restrict__ Wo, const float* __restrict__ bv,
    const float* __restrict__ x,
    u32* __restrict__ MkT, u32* __restrict__ MvT,
    float* __restrict__ Cb, float* __restrict__ bvoP,
    u32* __restrict__ xb) {
  const int t = threadIdx.x;
  const int bid = blockIdx.x;
  if (bid >= 128) {              // ---- x -> bf16 (16 blocks) ----
    const int sub = bid - 128;
    #pragma unroll
    for (int i = 0; i < 8; ++i) {
      size_t base = (size_t)sub * 16384 + i * 2048 + t * 8;
      float4 a = *(const float4*)&x[base];
      float4 b = *(const float4*)&x[base + 4];
      uint4 o;
      o.x = pack2(a.x, a.y); o.y = pack2(a.z, a.w);
      o.z = pack2(b.x, b.y); o.w = pack2(b.z, b.w);
      *(uint4*)&xb[base >> 1] = o;
    }
    return;
  }
  __shared__ float LA[64][68];
  __shared__ float LB[64][68];
  __shared__ float bvec[64];
  const bool isMk = bid < 64;
  const int sub = isMk ? bid : bid - 64;
  const int h = sub >> 3;
  const int tile = (sub & 7) * 64;

  for (int r = 0; r < 4; ++r) {
    int idx = t + 256 * r;
    int row = idx >> 4, dq = idx & 15;
    const float* src = isMk ? (Wq + (size_t)(tile + row) * 512 + h * 64 + dq * 4)
                            : (Wv + (size_t)row * 512 + h * 64 + dq * 4);
    float4 v = *(const float4*)src;
    LA[dq * 4 + 0][row] = v.x; LA[dq * 4 + 1][row] = v.y;
    LA[dq * 4 + 2][row] = v.z; LA[dq * 4 + 3][row] = v.w;
  }
  for (int r = 0; r < 4; ++r) {
    int idx = t + 256 * r;
    if (isMk) {
      int c = idx >> 4, dq = idx & 15;
      float4 v = *(const float4*)&Wk[(size_t)c * 512 + h * 64 + dq * 4];
      LB[dq * 4 + 0][c] = v.x; LB[dq * 4 + 1][c] = v.y;
      LB[dq * 4 + 2][c] = v.z; LB[dq * 4 + 3][c] = v.w;
    } else {
      int d = idx >> 4, fq = idx & 15;
      float4 v = *(const float4*)&Wo[(size_t)(h * 64 + d) * 512 + tile + fq * 4];
      *(float4*)&LB[d][fq * 4] = v;
    }
  }
  if (t < 16) {
    const float* bsrc = isMk ? bq : bv;
    float4 v = *(const float4*)&bsrc[h * 64 + t * 4];
    bvec[t * 4 + 0] = v.x; bvec[t * 4 + 1] = v.y;
    bvec[t * 4 + 2] = v.z; bvec[t * 4 + 3] = v.w;
  }
  __syncthreads();

  const int r0 = (t >> 4) * 4;
  const int c0 = (t & 15) * 4;
  float acc[4][4] = {};
  #pragma unroll 8
  for (int d = 0; d < 64; ++d) {
    float4 a = *(float4*)&LA[d][r0];
    float4 b = *(float4*)&LB[d][c0];
    acc[0][0] += a.x * b.x; acc[0][1] += a.x * b.y; acc[0][2] += a.x * b.z; acc[0][3] += a.x * b.w;
    acc[1][0] += a.y * b.x; acc[1][1] += a.y * b.y; acc[1][2] += a.y * b.z; acc[1][3] += a.y * b.w;
    acc[2][0] += a.z * b.x; acc[2][1] += a.z * b.y; acc[2][2] += a.z * b.z; acc[2][3] += a.z * b.w;
    acc[3][0] += a.w * b.x; acc[3][1] += a.w * b.y; acc[3][2] += a.w * b.z; acc[3][3] += a.w * b.w;
  }
  if (isMk) {
    // MkT[hc][e]: rows hc, contiguous e (bf16 pairs)
    #pragma unroll
    for (int j = 0; j < 4; ++j) {
      int hc = h * 64 + c0 + j;
      uint2 o = make_uint2(pack2(acc[0][j], acc[1][j]), pack2(acc[2][j], acc[3][j]));
      *(uint2*)&MkT[(size_t)hc * 256 + ((tile + r0) >> 1)] = o;
    }
    if ((sub & 7) == 0 && t < 64) {
      float s = 0.f;
      for (int d = 0; d < 64; ++d) s += bvec[d] * LB[d][t];
      Cb[h * 64 + t] = s;
    }
  } else {
    // MvT[f][hc]: rows f, contiguous hc
    #pragma unroll
    for (int j = 0; j < 4; ++j) {
      int f = tile + c0 + j;
      uint2 o = make_uint2(pack2(acc[0][j], acc[1][j]), pack2(acc[2][j], acc[3][j]));
      *(uint2*)&MvT[(size_t)f * 256 + ((h * 64 + r0) >> 1)] = o;
    }
    if (t < 64) {
      float s = 0.f;
      for (int d = 0; d < 64; ++d) s += bvec[d] * LB[d][t];
      bvoP[h * 512 + tile + t] = s;
    }
  }
}

// ---------------- G: 512x512x512 bf16 MFMA GEMM, split-K=4 ----------------
// grid (8 n, 8 m, 4 kz); block tile 64x64, K=128 per block, single-shot staging.
// A: bf16 row-major [512][512] (k contiguous).  Bt: bf16 [n][k].  P: fp32 partials.
__global__ __launch_bounds__(256) void k_gemm_bf16(
    const u32* __restrict__ A, const u32* __restrict__ Bt,
    float* __restrict__ P) {
  __shared__ ushort As[64 * 136];   // [row m][k], stride 136 bf16 (272B, 16B-aligned, 2-way banks)
  __shared__ ushort Bs[64 * 136];   // [row n][k]
  const int t = threadIdx.x;
  const int n0 = blockIdx.x * 64, m0 = blockIdx.y * 64;
  const int kz = blockIdx.z;
  const int ku = kz * 64;           // k-offset in u32 (128 bf16)
  #pragma unroll
  for (int it = 0; it < 4; ++it) {
    int idx = t + 256 * it;
    int row = idx >> 4, seg = idx & 15;
    uint4 va = *(const uint4*)&A[(size_t)(m0 + row) * 256 + ku + seg * 4];
    *(uint4*)&As[row * 136 + seg * 8] = va;
    uint4 vb = *(const uint4*)&Bt[(size_t)(n0 + row) * 256 + ku + seg * 4];
    *(uint4*)&Bs[row * 136 + seg * 8] = vb;
  }
  __syncthreads();
  const int lane = t & 63, w = t >> 6;
  const int lr = lane & 15, lg = lane >> 4;
  f32x4 acc[4] = {};
  #pragma unroll
  for (int kk = 0; kk < 4; ++kk) {
    U4 a; a.u = *(const uint4*)&As[(w * 16 + lr) * 136 + kk * 32 + lg * 8];
    #pragma unroll
    for (int nt = 0; nt < 4; ++nt) {
      U4 b; b.u = *(const uint4*)&Bs[(nt * 16 + lr) * 136 + kk * 32 + lg * 8];
      acc[nt] = __builtin_amdgcn_mfma_f32_16x16x32_bf16(a.v, b.v, acc[nt], 0, 0, 0);
    }
  }
  float* out = P + (size_t)kz * 262144 + (size_t)(m0 + w * 16 + lg * 4) * 512 + n0 + lr;
  #pragma unroll
  for (int nt = 0; nt < 4; ++nt)
    #pragma unroll
    for (int r = 0; r < 4; ++r)
      out[(size_t)r * 512 + nt * 16] = acc[nt][r];
}

// ---------------- K2: scores MFMA -> softmax -> wp MFMA ----------------
__global__ __launch_bounds__(256) void k2_attn(
    const float* __restrict__ pair, const float* __restrict__ QWkP,
    const float* __restrict__ Cb, u32* __restrict__ wp) {
  __shared__ u32 PuU[256 * 36];     // P[j][c] bf16 c-pairs (32 used + 4 pad); later wb + wpF
  __shared__ u32 PtU[64 * 132];     // P^T[c][j] bf16 j-pairs, XOR-swizzled; pad cols 128..131 = red
  __shared__ ushort qkb[16 * 72];   // qk/8 bf16, rows 8..15 zero
  const int t = threadIdx.x, bi = blockIdx.x;
  const int lane = t & 63, w = t >> 6;
  const int lr = lane & 15, lg = lane >> 4;
  const float* pr = pair + (size_t)bi * 16384;

  { // qkb: sum 4 split-K partials + Cb, scale by 1/sqrt(64)
    int h = t >> 4, c0 = (t & 15) * 4;
    float4 q = make_float4(0.f, 0.f, 0.f, 0.f);
    if (h < 8) {
      size_t base = (size_t)bi * 512 + h * 64 + c0;
      #pragma unroll
      for (int z = 0; z < 4; ++z) {
        float4 v = *(const float4*)&QWkP[(size_t)z * 262144 + base];
        q.x += v.x; q.y += v.y; q.z += v.z; q.w += v.w;
      }
      float4 cb = *(const float4*)&Cb[h * 64 + c0];
      q.x = (q.x + cb.x) * 0.125f; q.y = (q.y + cb.y) * 0.125f;
      q.z = (q.z + cb.z) * 0.125f; q.w = (q.w + cb.w) * 0.125f;
    }
    *(uint2*)&qkb[h * 72 + c0] = make_uint2(pack2(q.x, q.y), pack2(q.z, q.w));
  }
  // pair staging: row-major (Pu) + transposed swizzled (Pt)
  #pragma unroll
  for (int r = 0; r < 8; ++r) {
    int task = t + 256 * r;
    int jp = task >> 4, cq = task & 15;
    const float* p0 = pr + (size_t)(2 * jp) * 64 + cq * 4;
    float4 a = *(const float4*)p0;
    float4 b = *(const float4*)(p0 + 64);
    *(uint2*)&PuU[(2 * jp) * 36 + cq * 2]     = make_uint2(pack2(a.x, a.y), pack2(a.z, a.w));
    *(uint2*)&PuU[(2 * jp + 1) * 36 + cq * 2] = make_uint2(pack2(b.x, b.y), pack2(b.z, b.w));
    int c = cq * 4;
    int col = jp ^ ((cq & 7) << 2);           // (c>>2)&7 == cq&7 for all 4 rows
    PtU[(c + 0) * 132 + col] = pack2(a.x, b.x);
    PtU[(c + 1) * 132 + col] = pack2(a.y, b.y);
    PtU[(c + 2) * 132 + col] = pack2(a.z, b.z);
    PtU[(c + 3) * 132 + col] = pack2(a.w, b.w);
  }
  __syncthreads();

  // ---- scores MFMA: wave w owns j in [w*64, w*64+64) ----
  f32x4 sc[4];
  {
    U4 bq0, bq1;
    bq0.u = *(const uint4*)&qkb[lr * 72 + lg * 8];
    bq1.u = *(const uint4*)&qkb[lr * 72 + 32 + lg * 8];
    #pragma unroll
    for (int jt = 0; jt < 4; ++jt) {
      int j0 = w * 64 + jt * 16;
      U4 a0, a1;
      a0.u = *(const uint4*)&PuU[(j0 + lr) * 36 + lg * 4];
      a1.u = *(const uint4*)&PuU[(j0 + lr) * 36 + 16 + lg * 4];
      f32x4 z = {0.f, 0.f, 0.f, 0.f};
      z = __builtin_amdgcn_mfma_f32_16x16x32_bf16(a0.v, bq0.v, z, 0, 0, 0);
      z = __builtin_amdgcn_mfma_f32_16x16x32_bf16(a1.v, bq1.v, z, 0, 0, 0);
      sc[jt] = z;   // lane: h = lr, j = j0 + lg*4 + reg
    }
  }
  // ---- softmax over j (per h = lr) ----
  float* redf = (float*)PtU;   // pad cols: redA rows 0..15, redB rows 16..31
  float m = -3.4e38f;
  #pragma unroll
  for (int jt = 0; jt < 4; ++jt)
    #pragma unroll
    for (int r = 0; r < 4; ++r) m = fmaxf(m, sc[jt][r]);
  m = fmaxf(m, __shfl_xor(m, 16, 64));
  m = fmaxf(m, __shfl_xor(m, 32, 64));
  if (lane < 16) redf[lane * 132 + 128 + w] = m;
  __syncthreads();
  float4 mr = *(const float4*)&redf[lr * 132 + 128];
  float M = fmaxf(fmaxf(mr.x, mr.y), fmaxf(mr.z, mr.w));
  float ev[4][4];
  float es = 0.f;
  #pragma unroll
  for (int jt = 0; jt < 4; ++jt)
    #pragma unroll
    for (int r = 0; r < 4; ++r) { ev[jt][r] = __expf(sc[jt][r] - M); es += ev[jt][r]; }
  es += __shfl_xor(es, 16, 64);
  es += __shfl_xor(es, 32, 64);
  if (lane < 16) redf[(16 + lane) * 132 + 128 + w] = es;
  __syncthreads();
  float4 zr = *(const float4*)&redf[(16 + lr) * 132 + 128];
  float rz = __builtin_amdgcn_rcpf(zr.x + zr.y + zr.z + zr.w);
  // write weights: wb[h][j] bf16 (overlays PuU; all PuU reads done before prev barrier)
  ushort* wb = (ushort*)PuU;
  #pragma unroll
  for (int jt = 0; jt < 4; ++jt) {
    int j0 = w * 64 + jt * 16 + lg * 4;
    uint2 o = make_uint2(pack2(ev[jt][0] * rz, ev[jt][1] * rz),
                         pack2(ev[jt][2] * rz, ev[jt][3] * rz));
    *(uint2*)&wb[lr * 264 + j0] = o;
  }
  __syncthreads();

  // ---- wp MFMA: wave w owns c in [w*16, w*16+16) ----
  f32x4 wacc = {0.f, 0.f, 0.f, 0.f};
  const int c = w * 16 + lr;
  const int cswz = (c >> 2) & 7;
  #pragma unroll
  for (int ks = 0; ks < 8; ++ks) {
    U4 a; a.u = *(const uint4*)&wb[lr * 264 + ks * 32 + lg * 8];
    int g = ks * 4 + lg;
    U4 b; b.u = *(const uint4*)&PtU[c * 132 + ((g ^ cswz) << 2)];
    wacc = __builtin_amdgcn_mfma_f32_16x16x32_bf16(a.v, b.v, wacc, 0, 0, 0);
  }
  // lane: h = lg*4 + reg (valid h<8 -> lanes 0..31), col c
  float* wpF = (float*)(PuU + 2112);   // [8][68], disjoint from wb region
  if (lane < 32) {
    #pragma unroll
    for (int r = 0; r < 4; ++r) wpF[(lg * 4 + r) * 68 + c] = wacc[r];
  }
  __syncthreads();
  if (t < 128) {
    int h = t >> 4, c0 = (t & 15) * 4;
    float4 v = *(const float4*)&wpF[h * 68 + c0];
    *(uint2*)&wp[(size_t)bi * 256 + h * 32 + (c0 >> 1)] =
        make_uint2(pack2(v.x, v.y), pack2(v.z, v.w));
  }
}

// ---------------- K4: residual + biases + LayerNorm ----------------
__global__ __launch_bounds__(256) void k4_ln(
    const float* __restrict__ GP, const float* __restrict__ bvoP,
    const float* __restrict__ bo, const float* __restrict__ x,
    const float* __restrict__ gamma, const float* __restrict__ beta,
    float* __restrict__ out) {
  __shared__ float red[2][4];
  const int t = threadIdx.x, bi = blockIdx.x;
  float y[2];
  #pragma unroll
  for (int r = 0; r < 2; ++r) {
    int f = t + 256 * r;
    float v = bo[f] + x[(size_t)bi * 512 + f];
    #pragma unroll
    for (int z = 0; z < 4; ++z) v += GP[(size_t)z * 262144 + (size_t)bi * 512 + f];
    #pragma unroll
    for (int h = 0; h < 8; ++h) v += bvoP[h * 512 + f];
    y[r] = v;
  }
  float s = y[0] + y[1];
  float q = y[0] * y[0] + y[1] * y[1];
  for (int o = 32; o; o >>= 1) { s += __shfl_xor(s, o, 64); q += __shfl_xor(q, o, 64); }
  const int wv = t >> 6, lane = t & 63;
  if (lane == 0) { red[0][wv] = s; red[1][wv] = q; }
  __syncthreads();
  float S = red[0][0] + red[0][1] + red[0][2] + red[0][3];
  float Qs = red[1][0] + red[1][1] + red[1][2] + red[1][3];
  float mu = S * (1.f / 512.f);
  float var = Qs * (1.f / 512.f) - mu * mu;
  float rstd = rsqrtf(var + 1e-5f);
  #pragma unroll
  for (int r = 0; r < 2; ++r) {
    int f = t + 256 * r;
    out[(size_t)bi * 512 + f] = (y[r] - mu) * rstd * gamma[f] + beta[f];
  }
}

extern "C" void kernel_launch(void* const* d_in, const int* in_sizes, int n_in,
                              void* d_out, int out_size, void* d_ws, size_t ws_size,
                              hipStream_t stream) {
  (void)in_sizes; (void)n_in; (void)out_size; (void)ws_size;
  const float* x     = (const float*)d_in[0];
  const float* pair  = (const float*)d_in[1];
  const float* Wq    = (const float*)d_in[2];
  const float* bq    = (const float*)d_in[3];
  const float* Wk    = (const float*)d_in[4];
  // d_in[5] = bk: Q.bk is constant over j -> cancels in softmax (verified round 1)
  const float* Wv    = (const float*)d_in[6];
  const float* bv    = (const float*)d_in[7];
  const float* Wo    = (const float*)d_in[8];
  const float* bo    = (const float*)d_in[9];
  const float* gamma = (const float*)d_in[10];
  const float* beta  = (const float*)d_in[11];

  float* ws   = (float*)d_ws;
  u32* MkT    = (u32*)ws;
  u32* MvT    = (u32*)(ws + 131072);
  u32* xb     = (u32*)(ws + 262144);
  u32* wp     = (u32*)(ws + 393216);
  float* Cb   = ws + 524288;
  float* bvoP = ws + 524800;
  float* QWkP = ws + 528896;      // 4 slices; reused as GP by G2
  float* GP   = QWkP;

  k0_prep<<<144, 256, 0, stream>>>(Wq, bq, Wk, Wv, Wo, bv, x, MkT, MvT, Cb, bvoP, xb);
  k_gemm_bf16<<<dim3(8, 8, 4), 256, 0, stream>>>(xb, MkT, QWkP);
  k2_attn<<<512, 256, 0, stream>>>(pair, QWkP, Cb, wp);
  k_gemm_bf16<<<dim3(8, 8, 4), 256, 0, stream>>>(wp, MvT, GP);
  k4_ln<<<512, 256, 0, stream>>>(GP, bvoP, bo, x, gamma, beta, (float*)d_out);
}